// Round 1
// baseline (61.158 us; speedup 1.0000x reference)
//
#include <hip/hip_runtime.h>
#include <math.h>

// Problem constants (x: (16, 1, 3, 1024, 1024) fp32)
#define W      1024            // columns
#define H      1024            // rows per batch image
#define NB     16              // batch
#define FRAME  (1024 * 1024)   // elements per frame
#define BSTR   (3 * FRAME)     // elements per batch (3 frames)
#define ROWS   (NB * H)        // 16384 flattened rows

// ---- order-preserving float <-> uint transforms (for exact atomic min/max) ----
__device__ __forceinline__ unsigned f2o(float f) {
    unsigned b = __float_as_uint(f);
    // sign set -> flip all bits; sign clear -> flip sign bit. Monotone map.
    return b ^ (unsigned)(((int)b >> 31) | (int)0x80000000);
}
__device__ __forceinline__ float o2f(unsigned u) {
    unsigned mask = (u & 0x80000000u) ? 0x80000000u : 0xFFFFFFFFu;
    return __uint_as_float(u ^ mask);
}

__device__ __forceinline__ float4 min4(float4 a, float4 b) {
    return make_float4(fminf(a.x, b.x), fminf(a.y, b.y), fminf(a.z, b.z), fminf(a.w, b.w));
}
__device__ __forceinline__ float4 max4(float4 a, float4 b) {
    return make_float4(fmaxf(a.x, b.x), fmaxf(a.y, b.y), fmaxf(a.z, b.z), fmaxf(a.w, b.w));
}

// sout value for flattened row r, loading frame0 (and frame2 only for r < H)
__device__ __forceinline__ float4 sout_val(const float* __restrict__ x, int r, int col) {
    int b = r >> 10;
    int hh = r & (H - 1);
    const float* p = x + (size_t)b * BSTR + ((size_t)hh << 10) + col;
    float4 f0 = *(const float4*)p;
    if (r < H) {
        float4 f2 = *(const float4*)(p + 2 * FRAME);
        return make_float4(f2.x - f0.x, f2.y - f0.y, f2.z - f0.z, f2.w - f0.w);
    }
    return f0;
}

// ---- Pass 1: per-column min/max (512 blocks: 4 col-groups x 128 row-chunks) ----
__global__ __launch_bounds__(256) void minmax_k(const float* __restrict__ x,
                                                unsigned* __restrict__ mn_u,
                                                unsigned* __restrict__ mx_u) {
    const int cg   = blockIdx.x & 3;    // column group, 256 cols each
    const int ch   = blockIdx.x >> 2;   // row chunk, 128 rows each
    const int lane = threadIdx.x & 63;
    const int wid  = threadIdx.x >> 6;  // wave id within block (0..3)
    const int col  = cg * 256 + lane * 4;

    const float INF = __builtin_inff();
    float4 vmin = make_float4(INF, INF, INF, INF);
    float4 vmax = make_float4(-INF, -INF, -INF, -INF);

    const int r0 = ch * (ROWS / 128);   // 128 rows per chunk
#pragma unroll 4
    for (int i = 0; i < 32; ++i) {
        int r = r0 + (i << 2) + wid;
        float4 v = sout_val(x, r, col);
        vmin = min4(vmin, v);
        vmax = max4(vmax, v);
    }

    __shared__ float4 smin[4][64];
    __shared__ float4 smax[4][64];
    smin[wid][lane] = vmin;
    smax[wid][lane] = vmax;
    __syncthreads();

    if (threadIdx.x < 64) {
        float4 m = min4(min4(smin[0][lane], smin[1][lane]),
                        min4(smin[2][lane], smin[3][lane]));
        float4 M = max4(max4(smax[0][lane], smax[1][lane]),
                        max4(smax[2][lane], smax[3][lane]));
        atomicMin(&mn_u[col + 0], f2o(m.x));
        atomicMin(&mn_u[col + 1], f2o(m.y));
        atomicMin(&mn_u[col + 2], f2o(m.z));
        atomicMin(&mn_u[col + 3], f2o(m.w));
        atomicMax(&mx_u[col + 0], f2o(M.x));
        atomicMax(&mx_u[col + 1], f2o(M.y));
        atomicMax(&mx_u[col + 2], f2o(M.z));
        atomicMax(&mx_u[col + 3], f2o(M.w));
    }
}

// ---- finalize: mn and 1/denom per column ----
__global__ void finalize_k(const unsigned* __restrict__ mn_u,
                           const unsigned* __restrict__ mx_u,
                           float* __restrict__ mn_f,
                           float* __restrict__ inv_f) {
    int c = blockIdx.x * blockDim.x + threadIdx.x;
    if (c < W) {
        float mn = o2f(mn_u[c]);
        float mx = o2f(mx_u[c]);
        float rng = mx - mn;
        float den = (rng == 0.0f) ? 1.0f : rng;  // _handle_zeros_in_scale
        mn_f[c] = mn;
        inv_f[c] = 1.0f / den;
    }
}

// ---- Pass 2: scaled output, grid-stride float4 ----
__global__ __launch_bounds__(256) void scale_k(const float* __restrict__ x,
                                               const float* __restrict__ mn_f,
                                               const float* __restrict__ inv_f,
                                               float* __restrict__ out) {
    const int total4 = (ROWS * W) / 4;  // 4,194,304
    const int stride = gridDim.x * blockDim.x;
    for (int i4 = blockIdx.x * blockDim.x + threadIdx.x; i4 < total4; i4 += stride) {
        int idx = i4 << 2;
        int r   = idx >> 10;
        int col = idx & (W - 1);
        float4 v = sout_val(x, r, col);
        float4 mn4 = *(const float4*)(mn_f + col);
        float4 iv4 = *(const float4*)(inv_f + col);
        float4 o = make_float4((v.x - mn4.x) * iv4.x,
                               (v.y - mn4.y) * iv4.y,
                               (v.z - mn4.z) * iv4.z,
                               (v.w - mn4.w) * iv4.w);
        *(float4*)(out + idx) = o;
    }
}

extern "C" void kernel_launch(void* const* d_in, const int* in_sizes, int n_in,
                              void* d_out, int out_size, void* d_ws, size_t ws_size,
                              hipStream_t stream) {
    const float* x = (const float*)d_in[0];
    float* out = (float*)d_out;

    // workspace layout: mn_u[1024] | mx_u[1024] | mn_f[1024] | inv_f[1024]  (16 KB)
    unsigned* mn_u = (unsigned*)d_ws;
    unsigned* mx_u = mn_u + W;
    float* mn_f = (float*)(mx_u + W);
    float* inv_f = mn_f + W;

    // init min to +inf-equivalent (0xFFFFFFFF), max to -inf-equivalent (0x0)
    hipMemsetAsync(mn_u, 0xFF, W * sizeof(unsigned), stream);
    hipMemsetAsync(mx_u, 0x00, W * sizeof(unsigned), stream);

    minmax_k<<<512, 256, 0, stream>>>(x, mn_u, mx_u);
    finalize_k<<<4, 256, 0, stream>>>(mn_u, mx_u, mn_f, inv_f);
    scale_k<<<2048, 256, 0, stream>>>(x, mn_f, inv_f, out);
}